// Round 1
// baseline (382.637 us; speedup 1.0000x reference)
//
#include <hip/hip_runtime.h>
#include <cstdint>

typedef __bf16 bf16;
typedef __bf16 bf16x8 __attribute__((ext_vector_type(8)));
typedef __bf16 bf16x4 __attribute__((ext_vector_type(4)));
typedef float  f32x4  __attribute__((ext_vector_type(4)));

#define HIDDEN 2304
#define NQ 2048
#define NKV 1024
#define SEQ 2048
#define NEGF -3.0e38f

// ---------------- RMSNorm + bf16 cast ----------------
__global__ __launch_bounds__(256) void rmsnorm_kernel(const float* __restrict__ x,
                                                      const float* __restrict__ w,
                                                      bf16* __restrict__ xb) {
  const int row = blockIdx.x, t = threadIdx.x;
  const float* xr = x + (size_t)row * HIDDEN;
  float v[9]; float ss = 0.f;
#pragma unroll
  for (int i = 0; i < 9; ++i) { v[i] = xr[t + i * 256]; ss += v[i] * v[i]; }
#pragma unroll
  for (int o = 32; o; o >>= 1) ss += __shfl_xor(ss, o, 64);
  __shared__ float wss[4];
  if ((t & 63) == 0) wss[t >> 6] = ss;
  __syncthreads();
  ss = wss[0] + wss[1] + wss[2] + wss[3];
  const float rs = rsqrtf(ss * (1.0f / HIDDEN) + 1e-6f);
  bf16* xo = xb + (size_t)row * HIDDEN;
#pragma unroll
  for (int i = 0; i < 9; ++i) xo[t + i * 256] = (bf16)(v[i] * rs * (1.0f + w[t + i * 256]));
}

// ---------------- f32 -> bf16 weight convert ----------------
__global__ __launch_bounds__(256) void cvt_kernel(const float* __restrict__ s, bf16* __restrict__ d, int n) {
  const int i = (blockIdx.x * 256 + threadIdx.x) * 4;
  if (i >= n) return;
  const float4 f = *(const float4*)(s + i);
  bf16x4 o; o.x = (bf16)f.x; o.y = (bf16)f.y; o.z = (bf16)f.z; o.w = (bf16)f.w;
  *(bf16x4*)(d + i) = o;
}

// ---------------- RoPE in-place on q and k (bf16) ----------------
__global__ __launch_bounds__(256) void rope_kernel(bf16* __restrict__ q, bf16* __restrict__ k,
                                                   const float* __restrict__ cosb,
                                                   const float* __restrict__ sinb) {
  const int tid = blockIdx.x * 256 + threadIdx.x;
  const int QN = 4096 * 8 * 128;
  const int KN = 4096 * 4 * 128;
  bf16* p; int row, d;
  if (tid < QN) {
    row = tid >> 10; const int rem = tid & 1023; d = rem & 127;
    p = q + (size_t)row * NQ + (rem >> 7) * 256 + d;
  } else {
    const int t2 = tid - QN; if (t2 >= KN) return;
    row = t2 >> 9; const int rem = t2 & 511; d = rem & 127;
    p = k + (size_t)row * NKV + (rem >> 7) * 256 + d;
  }
  const size_t cb = (size_t)row * 256 + d;
  const float c0 = cosb[cb], s0 = sinb[cb], c1 = cosb[cb + 128], s1 = sinb[cb + 128];
  const float a = (float)p[0], b = (float)p[128];
  p[0]   = (bf16)(a * c0 - b * s0);
  p[128] = (bf16)(b * c1 + a * s1);
}

// ---------------- bf16 GEMM, C[M,N] = A[M,K] * B[N,K]^T ----------------
// MODE 0: store bf16 row-major. MODE 1: store bf16 transposed V layout
// [B][NKV][SEQ]. MODE 2: store f32 + residual.
template<int MODE>
__global__ __launch_bounds__(256) void gemm_bt(const bf16* __restrict__ A, const bf16* __restrict__ B,
                                               void* __restrict__ C, const float* __restrict__ resid,
                                               int M, int N, int K) {
  __shared__ bf16 As[128][72];
  __shared__ bf16 Bs[128][72];
  const int t = threadIdx.x, lane = t & 63, w = t >> 6;
  const int wr = w >> 1, wc = w & 1;
  const int r16 = lane & 15, g = lane >> 4;
  const int m0 = blockIdx.x * 128, n0 = blockIdx.y * 128;
  f32x4 acc[4][4] = {};
  for (int k0 = 0; k0 < K; k0 += 64) {
    __syncthreads();
#pragma unroll
    for (int it = 0; it < 4; ++it) {
      const int flat = it * 2048 + t * 8;
      const int row = flat >> 6, kk = flat & 63;
      *(bf16x8*)&As[row][kk] = *(const bf16x8*)&A[(size_t)(m0 + row) * K + k0 + kk];
      *(bf16x8*)&Bs[row][kk] = *(const bf16x8*)&B[(size_t)(n0 + row) * K + k0 + kk];
    }
    __syncthreads();
#pragma unroll
    for (int ks = 0; ks < 2; ++ks) {
      bf16x8 af[4], bfv[4];
#pragma unroll
      for (int i = 0; i < 4; ++i) {
        af[i]  = *(const bf16x8*)&As[wr * 64 + i * 16 + r16][ks * 32 + g * 8];
        bfv[i] = *(const bf16x8*)&Bs[wc * 64 + i * 16 + r16][ks * 32 + g * 8];
      }
#pragma unroll
      for (int i = 0; i < 4; ++i)
#pragma unroll
        for (int j = 0; j < 4; ++j)
          acc[i][j] = __builtin_amdgcn_mfma_f32_16x16x32_bf16(af[i], bfv[j], acc[i][j], 0, 0, 0);
    }
  }
#pragma unroll
  for (int i = 0; i < 4; ++i)
#pragma unroll
    for (int j = 0; j < 4; ++j) {
      const int mb = m0 + wr * 64 + i * 16 + g * 4;
      const int n = n0 + wc * 64 + j * 16 + r16;
#pragma unroll
      for (int e = 0; e < 4; ++e) {
        const int m = mb + e;
        const float vv = acc[i][j][e];
        if constexpr (MODE == 0) {
          ((bf16*)C)[(size_t)m * N + n] = (bf16)vv;
        } else if constexpr (MODE == 1) {
          const int bb = m >> 11, s = m & 2047;
          ((bf16*)C)[((size_t)bb * NKV + n) * SEQ + s] = (bf16)vv;
        } else {
          ((float*)C)[(size_t)m * N + n] = vv + resid[(size_t)m * N + n];
        }
      }
    }
}

// ---------------- Flash attention: QT=64 (4 waves x 16 rows), KT=32 ----------------
__global__ __launch_bounds__(256) void attn_kernel(const bf16* __restrict__ q, const bf16* __restrict__ k,
                                                   const bf16* __restrict__ vt, bf16* __restrict__ ao) {
  __shared__ bf16 smem[21248];
  bf16* const qs  = smem;          // [64][264] (phase 1 only)
  bf16* const ksl = smem;          // [32][264]
  bf16* const vtl = smem + 8448;   // [256][40]
  bf16* const pl  = smem + 18688;  // [4][16][40]
  const int qt = blockIdx.x, h = blockIdx.y, b = blockIdx.z;
  const int kvh = h >> 1;
  const int t = threadIdx.x, lane = t & 63, w = t >> 6;
  const int r16 = lane & 15, g = lane >> 4;
  const int i_base = qt * 64;

  {  // stage Q tile 64x256
    const bf16* qg = q + ((size_t)(b * SEQ + i_base)) * NQ + h * 256;
#pragma unroll
    for (int it = 0; it < 8; ++it) {
      const int flat = it * 2048 + t * 8;
      const int row = flat >> 8, dd = flat & 255;
      *(bf16x8*)&qs[row * 264 + dd] = *(const bf16x8*)&qg[(size_t)row * NQ + dd];
    }
  }
  __syncthreads();
  bf16x8 aq[8];
#pragma unroll
  for (int c = 0; c < 8; ++c) aq[c] = *(const bf16x8*)&qs[(w * 16 + r16) * 264 + c * 32 + g * 8];

  f32x4 oacc[16] = {};
  float mrun[4] = {NEGF, NEGF, NEGF, NEGF};
  float lrun[4] = {0.f, 0.f, 0.f, 0.f};
  int jb = i_base - 1023; if (jb < 0) jb = 0; jb &= ~31;
  const int je = i_base + 63;
  const bf16* kg = k + (size_t)b * SEQ * NKV + kvh * 256;
  const bf16* vg = vt + ((size_t)b * NKV + kvh * 256) * SEQ;

  for (int j0 = jb; j0 <= je; j0 += 32) {
    __syncthreads();
#pragma unroll
    for (int it = 0; it < 4; ++it) {  // stage K 32x256 and V^T 256x32
      const int flat = it * 2048 + t * 8;
      const int row = flat >> 8, dd = flat & 255;
      *(bf16x8*)&ksl[row * 264 + dd] = *(const bf16x8*)&kg[(size_t)(j0 + row) * NKV + dd];
      const int vd = flat >> 5, vj = flat & 31;
      *(bf16x8*)&vtl[vd * 40 + vj] = *(const bf16x8*)&vg[(size_t)vd * SEQ + j0 + vj];
    }
    __syncthreads();

    f32x4 sc0 = {}, sc1 = {};
#pragma unroll
    for (int c = 0; c < 8; ++c) {
      const bf16x8 b0 = *(const bf16x8*)&ksl[r16 * 264 + c * 32 + g * 8];
      const bf16x8 b1 = *(const bf16x8*)&ksl[(16 + r16) * 264 + c * 32 + g * 8];
      sc0 = __builtin_amdgcn_mfma_f32_16x16x32_bf16(aq[c], b0, sc0, 0, 0, 0);
      sc1 = __builtin_amdgcn_mfma_f32_16x16x32_bf16(aq[c], b1, sc1, 0, 0, 0);
    }
#pragma unroll
    for (int e = 0; e < 4; ++e) {
      const int irow = i_base + w * 16 + g * 4 + e;
      float v0 = 50.0f * tanhf(sc0[e] * (0.0625f * 0.02f));
      float v1 = 50.0f * tanhf(sc1[e] * (0.0625f * 0.02f));
      const int jg0 = j0 + r16, jg1 = j0 + 16 + r16;
      if (jg0 > irow || irow - jg0 >= 1024) v0 = NEGF;
      if (jg1 > irow || irow - jg1 >= 1024) v1 = NEGF;
      float mx = fmaxf(v0, v1);
#pragma unroll
      for (int o = 1; o < 16; o <<= 1) mx = fmaxf(mx, __shfl_xor(mx, o, 64));
      const float mn = fmaxf(mrun[e], mx);
      const float mns = (mn < -1e29f) ? 0.f : mn;
      const float corr = __expf(mrun[e] - mns);
      float p0 = __expf(v0 - mns), p1 = __expf(v1 - mns);
      const bf16 p0b = (bf16)p0, p1b = (bf16)p1;
      p0 = (float)p0b; p1 = (float)p1b;
      float rsum = p0 + p1;
#pragma unroll
      for (int o = 1; o < 16; o <<= 1) rsum += __shfl_xor(rsum, o, 64);
      lrun[e] = lrun[e] * corr + rsum;
      mrun[e] = mn;
#pragma unroll
      for (int nf = 0; nf < 16; ++nf) oacc[nf][e] *= corr;
      pl[w * 640 + (g * 4 + e) * 40 + r16] = p0b;
      pl[w * 640 + (g * 4 + e) * 40 + 16 + r16] = p1b;
    }
    __syncthreads();
    const bf16x8 pa = *(const bf16x8*)&pl[w * 640 + r16 * 40 + g * 8];
#pragma unroll
    for (int nf = 0; nf < 16; ++nf) {
      const bf16x8 vb = *(const bf16x8*)&vtl[(nf * 16 + r16) * 40 + g * 8];
      oacc[nf] = __builtin_amdgcn_mfma_f32_16x16x32_bf16(pa, vb, oacc[nf], 0, 0, 0);
    }
  }
  float inv[4];
#pragma unroll
  for (int e = 0; e < 4; ++e) inv[e] = 1.0f / lrun[e];
  bf16* aor = ao + ((size_t)(b * SEQ + i_base + w * 16)) * NQ + h * 256;
#pragma unroll
  for (int nf = 0; nf < 16; ++nf)
#pragma unroll
    for (int e = 0; e < 4; ++e)
      aor[(size_t)(g * 4 + e) * NQ + nf * 16 + r16] = (bf16)(oacc[nf][e] * inv[e]);
}

extern "C" void kernel_launch(void* const* d_in, const int* in_sizes, int n_in,
                              void* d_out, int out_size, void* d_ws, size_t ws_size,
                              hipStream_t stream) {
  const float* hs   = (const float*)d_in[0];
  const float* cosb = (const float*)d_in[1];
  const float* sinb = (const float*)d_in[2];
  const float* rw   = (const float*)d_in[3];
  const float* Wq   = (const float*)d_in[4];
  const float* Wk   = (const float*)d_in[5];
  const float* Wv   = (const float*)d_in[6];
  const float* Wo   = (const float*)d_in[7];
  float* out = (float*)d_out;
  char* ws = (char*)d_ws;

  bf16* xb  = (bf16*)(ws);             // 4096x2304
  bf16* wqb = (bf16*)(ws + 18874368);  // 2048x2304
  bf16* wkb = (bf16*)(ws + 28311552);  // 1024x2304
  bf16* wvb = (bf16*)(ws + 33030144);  // 1024x2304
  bf16* wob = (bf16*)(ws + 37748736);  // 2304x2048
  bf16* qg  = (bf16*)(ws + 47185920);  // 4096x2048
  bf16* kg  = (bf16*)(ws + 63963136);  // 4096x1024
  bf16* vtg = (bf16*)(ws + 72351744);  // [2][1024][2048]
  bf16* ag  = (bf16*)(ws + 80740352);  // 4096x2048

  rmsnorm_kernel<<<4096, 256, 0, stream>>>(hs, rw, xb);
  cvt_kernel<<<(2048 * 2304 / 4 + 255) / 256, 256, 0, stream>>>(Wq, wqb, 2048 * 2304);
  cvt_kernel<<<(1024 * 2304 / 4 + 255) / 256, 256, 0, stream>>>(Wk, wkb, 1024 * 2304);
  cvt_kernel<<<(1024 * 2304 / 4 + 255) / 256, 256, 0, stream>>>(Wv, wvb, 1024 * 2304);
  cvt_kernel<<<(2304 * 2048 / 4 + 255) / 256, 256, 0, stream>>>(Wo, wob, 2304 * 2048);
  gemm_bt<0><<<dim3(32, 16), 256, 0, stream>>>(xb, wqb, qg, nullptr, 4096, 2048, 2304);
  gemm_bt<0><<<dim3(32, 8), 256, 0, stream>>>(xb, wkb, kg, nullptr, 4096, 1024, 2304);
  gemm_bt<1><<<dim3(32, 8), 256, 0, stream>>>(xb, wvb, vtg, nullptr, 4096, 1024, 2304);
  rope_kernel<<<(4096 * 8 * 128 + 4096 * 4 * 128) / 256, 256, 0, stream>>>(qg, kg, cosb, sinb);
  attn_kernel<<<dim3(32, 8, 2), 256, 0, stream>>>(qg, kg, vtg, ag);
  gemm_bt<2><<<dim3(32, 18), 256, 0, stream>>>(ag, wob, out, hs, 4096, 2304, 2048);
}

// Round 2
// 333.715 us; speedup vs baseline: 1.1466x; 1.1466x over previous
//
#include <hip/hip_runtime.h>
#include <cstdint>

typedef __bf16 bf16;
typedef __bf16 bf16x8 __attribute__((ext_vector_type(8)));
typedef __bf16 bf16x4 __attribute__((ext_vector_type(4)));
typedef float  f32x4  __attribute__((ext_vector_type(4)));

#define HIDDEN 2304
#define NQ 2048
#define NKV 1024
#define SEQ 2048

typedef __attribute__((address_space(1))) void gv_t;
typedef __attribute__((address_space(3))) void lv_t;
__device__ __forceinline__ void gld16(const void* g, void* l) {
  __builtin_amdgcn_global_load_lds((gv_t*)g, (lv_t*)l, 16, 0, 0);
}

// ---------------- RMSNorm + bf16 cast ----------------
__global__ __launch_bounds__(256) void rmsnorm_kernel(const float* __restrict__ x,
                                                      const float* __restrict__ w,
                                                      bf16* __restrict__ xb) {
  const int row = blockIdx.x, t = threadIdx.x;
  const float* xr = x + (size_t)row * HIDDEN;
  float v[9]; float ss = 0.f;
#pragma unroll
  for (int i = 0; i < 9; ++i) { v[i] = xr[t + i * 256]; ss += v[i] * v[i]; }
#pragma unroll
  for (int o = 32; o; o >>= 1) ss += __shfl_xor(ss, o, 64);
  __shared__ float wss[4];
  if ((t & 63) == 0) wss[t >> 6] = ss;
  __syncthreads();
  ss = wss[0] + wss[1] + wss[2] + wss[3];
  const float rs = rsqrtf(ss * (1.0f / HIDDEN) + 1e-6f);
  bf16* xo = xb + (size_t)row * HIDDEN;
#pragma unroll
  for (int i = 0; i < 9; ++i) xo[t + i * 256] = (bf16)(v[i] * rs * (1.0f + w[t + i * 256]));
}

// ---------------- f32 -> bf16 weight convert ----------------
__global__ __launch_bounds__(256) void cvt_kernel(const float* __restrict__ s, bf16* __restrict__ d, int n) {
  const int i = (blockIdx.x * 256 + threadIdx.x) * 4;
  if (i >= n) return;
  const float4 f = *(const float4*)(s + i);
  bf16x4 o; o.x = (bf16)f.x; o.y = (bf16)f.y; o.z = (bf16)f.z; o.w = (bf16)f.w;
  *(bf16x4*)(d + i) = o;
}

// ---------------- RoPE in-place on q and k (bf16) ----------------
__global__ __launch_bounds__(256) void rope_kernel(bf16* __restrict__ q, bf16* __restrict__ k,
                                                   const float* __restrict__ cosb,
                                                   const float* __restrict__ sinb) {
  const int tid = blockIdx.x * 256 + threadIdx.x;
  const int QN = 4096 * 8 * 128;
  const int KN = 4096 * 4 * 128;
  bf16* p; int row, d;
  if (tid < QN) {
    row = tid >> 10; const int rem = tid & 1023; d = rem & 127;
    p = q + (size_t)row * NQ + (rem >> 7) * 256 + d;
  } else {
    const int t2 = tid - QN; if (t2 >= KN) return;
    row = t2 >> 9; const int rem = t2 & 511; d = rem & 127;
    p = k + (size_t)row * NKV + (rem >> 7) * 256 + d;
  }
  const size_t cb = (size_t)row * 256 + d;
  const float c0 = cosb[cb], s0 = sinb[cb], c1 = cosb[cb + 128], s1 = sinb[cb + 128];
  const float a = (float)p[0], b = (float)p[128];
  p[0]   = (bf16)(a * c0 - b * s0);
  p[128] = (bf16)(b * c1 + a * s1);
}

// ---------------- bf16 GEMM (m97 structure), C[M,N] = A[M,K] * B[N,K]^T ----
// MODE 0: bf16 row-major into C (ld = N).
// MODE 1: fused K/V: n0<1024 -> K row-major (ld=1024) into C; n0>=1024 ->
//         V transposed [B][1024][SEQ] into C2.
// MODE 2: f32 + residual into C.
template<int MODE>
__global__ __launch_bounds__(256) void gemm_bt(const bf16* __restrict__ A, const bf16* __restrict__ B,
                                               void* __restrict__ C, void* __restrict__ C2,
                                               const float* __restrict__ resid,
                                               int M, int N, int K) {
  __shared__ bf16 As[128 * 64];
  __shared__ bf16 Bs[128 * 64];
  const int t = threadIdx.x, lane = t & 63, w = t >> 6;
  const int wr = w >> 1, wc = w & 1;
  const int r16 = lane & 15, g = lane >> 4;
  const int m0 = blockIdx.x * 128, n0 = blockIdx.y * 128;
  f32x4 acc[4][4] = {};
  for (int k0 = 0; k0 < K; k0 += 64) {
    __syncthreads();
#pragma unroll
    for (int c = 0; c < 4; ++c) {
      const int o = c * 4096 + w * 1024 + lane * 16;   // byte offset in 16KB tile
      const int row = o >> 7, col = (o & 127) >> 1;    // row, bf16 col
      gld16(&A[(size_t)(m0 + row) * K + k0 + col], (char*)As + o);
      gld16(&B[(size_t)(n0 + row) * K + k0 + col], (char*)Bs + o);
    }
    __syncthreads();
#pragma unroll
    for (int ks = 0; ks < 2; ++ks) {
      bf16x8 af[4], bfv[4];
#pragma unroll
      for (int i = 0; i < 4; ++i) {
        af[i]  = *(const bf16x8*)&As[(wr * 64 + i * 16 + r16) * 64 + ks * 32 + g * 8];
        bfv[i] = *(const bf16x8*)&Bs[(wc * 64 + i * 16 + r16) * 64 + ks * 32 + g * 8];
      }
#pragma unroll
      for (int i = 0; i < 4; ++i)
#pragma unroll
        for (int j = 0; j < 4; ++j)
          acc[i][j] = __builtin_amdgcn_mfma_f32_16x16x32_bf16(af[i], bfv[j], acc[i][j], 0, 0, 0);
    }
  }
#pragma unroll
  for (int i = 0; i < 4; ++i)
#pragma unroll
    for (int j = 0; j < 4; ++j) {
      const int mb = m0 + wr * 64 + i * 16 + g * 4;
      const int n = n0 + wc * 64 + j * 16 + r16;
#pragma unroll
      for (int e = 0; e < 4; ++e) {
        const int m = mb + e;
        const float vv = acc[i][j][e];
        if constexpr (MODE == 0) {
          ((bf16*)C)[(size_t)m * N + n] = (bf16)vv;
        } else if constexpr (MODE == 1) {
          if (n0 < 1024) {
            ((bf16*)C)[(size_t)m * 1024 + n] = (bf16)vv;
          } else {
            const int bb = m >> 11, s = m & 2047, col = n - 1024;
            ((bf16*)C2)[((size_t)bb * 1024 + col) * SEQ + s] = (bf16)vv;
          }
        } else {
          ((float*)C)[(size_t)m * N + n] = vv + resid[(size_t)m * N + n];
        }
      }
    }
}

// ---------------- attention tile loads (K 32x256, V^T 256x32) ----------------
__device__ __forceinline__ void attn_load(const bf16* __restrict__ kgp, const bf16* __restrict__ vgp,
                                          int j0, int t, bf16x8* kr, bf16x8* vr) {
#pragma unroll
  for (int it = 0; it < 4; ++it) {
    const int flat = it * 2048 + t * 8;
    kr[it] = *(const bf16x8*)&kgp[(size_t)((flat >> 8) + j0) * NKV + (flat & 255)];
    vr[it] = *(const bf16x8*)&vgp[(size_t)(flat >> 5) * SEQ + j0 + (flat & 31)];
  }
}

// ---------------- Flash attention: QT=64 (4 waves x 16 rows), KT=32 --------
// No online max: softcap bounds scores to [-50,50] and the (always-allowed)
// diagonal has score >= 0, so fixed shift M=50 is safe: p = exp(v-50) with
// p_diag >= e^-50 (normal). p = exp(-100/(e^{2y}+1)), y = s*SCALING/SOFTCAP.
__global__ __launch_bounds__(256) void attn_kernel(const bf16* __restrict__ q, const bf16* __restrict__ k,
                                                   const bf16* __restrict__ vt, bf16* __restrict__ ao) {
  __shared__ bf16 smem[21248];
  bf16* const qs  = smem;          // [64][264] (phase 1 only)
  bf16* const ksl = smem;          // [32][264]
  bf16* const vtl = smem + 8448;   // [256][40]
  bf16* const pl  = smem + 18688;  // [4][16][40]
  int qt = blockIdx.x;
  const int h = blockIdx.y, b = blockIdx.z;
  if (b) qt = 31 - qt;             // pair heavy+light q-tiles across the grid
  const int kvh = h >> 1;
  const int t = threadIdx.x, lane = t & 63, w = t >> 6;
  const int r16 = lane & 15, g = lane >> 4;
  const int i_base = qt * 64;

  {  // stage Q tile 64x256
    const bf16* qg = q + ((size_t)(b * SEQ + i_base)) * NQ + h * 256;
#pragma unroll
    for (int it = 0; it < 8; ++it) {
      const int flat = it * 2048 + t * 8;
      const int row = flat >> 8, dd = flat & 255;
      *(bf16x8*)&qs[row * 264 + dd] = *(const bf16x8*)&qg[(size_t)row * NQ + dd];
    }
  }
  __syncthreads();
  bf16x8 aq[8];
#pragma unroll
  for (int c = 0; c < 8; ++c) aq[c] = *(const bf16x8*)&qs[(w * 16 + r16) * 264 + c * 32 + g * 8];

  f32x4 oacc[16] = {};
  float lrun[4] = {0.f, 0.f, 0.f, 0.f};
  int jb = i_base - 1023; if (jb < 0) jb = 0; jb &= ~31;
  const int je = i_base + 63;
  const bf16* kg = k + (size_t)b * SEQ * NKV + kvh * 256;
  const bf16* vg = vt + ((size_t)b * NKV + kvh * 256) * SEQ;

  bf16x8 kr[4], vr[4];
  attn_load(kg, vg, jb, t, kr, vr);

  for (int j0 = jb; j0 <= je; j0 += 32) {
    __syncthreads();
#pragma unroll
    for (int it = 0; it < 4; ++it) {  // regs -> LDS
      const int flat = it * 2048 + t * 8;
      *(bf16x8*)&ksl[(flat >> 8) * 264 + (flat & 255)] = kr[it];
      *(bf16x8*)&vtl[(flat >> 5) * 40 + (flat & 31)] = vr[it];
    }
    __syncthreads();
    const int jn = (j0 + 32 <= je) ? (j0 + 32) : j0;
    attn_load(kg, vg, jn, t, kr, vr);  // prefetch next tile (hides under compute)

    f32x4 sc0 = {}, sc1 = {};
#pragma unroll
    for (int c = 0; c < 8; ++c) {
      const bf16x8 b0 = *(const bf16x8*)&ksl[r16 * 264 + c * 32 + g * 8];
      const bf16x8 b1 = *(const bf16x8*)&ksl[(16 + r16) * 264 + c * 32 + g * 8];
      sc0 = __builtin_amdgcn_mfma_f32_16x16x32_bf16(aq[c], b0, sc0, 0, 0, 0);
      sc1 = __builtin_amdgcn_mfma_f32_16x16x32_bf16(aq[c], b1, sc1, 0, 0, 0);
    }
    const bool full = (j0 + 31 <= i_base) && (i_base + 63 - j0 < 1024);
#pragma unroll
    for (int e = 0; e < 4; ++e) {
      const float t0 = __expf(sc0[e] * 0.0025f);
      const float t1 = __expf(sc1[e] * 0.0025f);
      float p0 = __expf(-100.0f / (t0 + 1.0f));
      float p1 = __expf(-100.0f / (t1 + 1.0f));
      if (!full) {
        const int irow = i_base + w * 16 + g * 4 + e;
        const int jg0 = j0 + r16, jg1 = j0 + 16 + r16;
        if (jg0 > irow || irow - jg0 >= 1024) p0 = 0.f;
        if (jg1 > irow || irow - jg1 >= 1024) p1 = 0.f;
      }
      const bf16 b0 = (bf16)p0, b1 = (bf16)p1;
      lrun[e] += (float)b0 + (float)b1;
      pl[w * 640 + (g * 4 + e) * 40 + r16] = b0;
      pl[w * 640 + (g * 4 + e) * 40 + 16 + r16] = b1;
    }
    // per-wave P buffer: same-wave LDS write->read dependency, no barrier needed
    const bf16x8 pa = *(const bf16x8*)&pl[w * 640 + r16 * 40 + g * 8];
#pragma unroll
    for (int nf = 0; nf < 16; ++nf) {
      const bf16x8 vb = *(const bf16x8*)&vtl[(nf * 16 + r16) * 40 + g * 8];
      oacc[nf] = __builtin_amdgcn_mfma_f32_16x16x32_bf16(pa, vb, oacc[nf], 0, 0, 0);
    }
  }
  float inv[4];
#pragma unroll
  for (int e = 0; e < 4; ++e) {
#pragma unroll
    for (int o = 1; o < 16; o <<= 1) lrun[e] += __shfl_xor(lrun[e], o, 64);
    inv[e] = 1.0f / lrun[e];
  }
  bf16* aor = ao + ((size_t)(b * SEQ + i_base + w * 16)) * NQ + h * 256;
#pragma unroll
  for (int nf = 0; nf < 16; ++nf)
#pragma unroll
    for (int e = 0; e < 4; ++e)
      aor[(size_t)(g * 4 + e) * NQ + nf * 16 + r16] = (bf16)(oacc[nf][e] * inv[e]);
}

extern "C" void kernel_launch(void* const* d_in, const int* in_sizes, int n_in,
                              void* d_out, int out_size, void* d_ws, size_t ws_size,
                              hipStream_t stream) {
  const float* hs   = (const float*)d_in[0];
  const float* cosb = (const float*)d_in[1];
  const float* sinb = (const float*)d_in[2];
  const float* rw   = (const float*)d_in[3];
  const float* Wq   = (const float*)d_in[4];
  const float* Wk   = (const float*)d_in[5];
  const float* Wv   = (const float*)d_in[6];
  const float* Wo   = (const float*)d_in[7];
  float* out = (float*)d_out;
  char* ws = (char*)d_ws;

  bf16* xb  = (bf16*)(ws);             // 4096x2304
  bf16* wqb = (bf16*)(ws + 18874368);  // 2048x2304
  bf16* wkb = (bf16*)(ws + 28311552);  // 1024x2304  (contiguous with wvb!)
  bf16* wvb = (bf16*)(ws + 33030144);  // 1024x2304
  bf16* wob = (bf16*)(ws + 37748736);  // 2304x2048
  bf16* qg  = (bf16*)(ws + 47185920);  // 4096x2048
  bf16* kg  = (bf16*)(ws + 63963136);  // 4096x1024
  bf16* vtg = (bf16*)(ws + 72351744);  // [2][1024][2048]
  bf16* ag  = (bf16*)(ws + 80740352);  // 4096x2048

  rmsnorm_kernel<<<4096, 256, 0, stream>>>(hs, rw, xb);
  cvt_kernel<<<(2048 * 2304 / 4 + 255) / 256, 256, 0, stream>>>(Wq, wqb, 2048 * 2304);
  cvt_kernel<<<(1024 * 2304 / 4 + 255) / 256, 256, 0, stream>>>(Wk, wkb, 1024 * 2304);
  cvt_kernel<<<(1024 * 2304 / 4 + 255) / 256, 256, 0, stream>>>(Wv, wvb, 1024 * 2304);
  cvt_kernel<<<(2304 * 2048 / 4 + 255) / 256, 256, 0, stream>>>(Wo, wob, 2304 * 2048);
  gemm_bt<0><<<dim3(32, 16), 256, 0, stream>>>(xb, wqb, qg, nullptr, nullptr, 4096, 2048, 2304);
  gemm_bt<1><<<dim3(32, 16), 256, 0, stream>>>(xb, wkb, kg, vtg, nullptr, 4096, 2048, 2304);
  rope_kernel<<<(4096 * 8 * 128 + 4096 * 4 * 128) / 256, 256, 0, stream>>>(qg, kg, cosb, sinb);
  attn_kernel<<<dim3(32, 8, 2), 256, 0, stream>>>(qg, kg, vtg, ag);
  gemm_bt<2><<<dim3(32, 18), 256, 0, stream>>>(ag, wob, out, nullptr, hs, 4096, 2304, 2048);
}